// Round 3
// baseline (609.301 us; speedup 1.0000x reference)
//
#include <hip/hip_runtime.h>
#include <hip/hip_fp16.h>

#define NBSHIFT 8
#define BSZ     256     // nodes per bucket
#define CAP     5120    // fixed bucket capacity (mean 4092, sigma 64 -> +16 sigma)
#define NSLICE  8       // channel slices: 128/8 = 16 ch = 32B/row; 3.2MB/slice fits XCD L2

typedef _Float16 f16x8 __attribute__((ext_vector_type(8)));
typedef float    f32x4 __attribute__((ext_vector_type(4)));

// ---------------- self-contained MFMA GEMM body ----------------
// Y is stored SLICED: Y[slice][n][16] with slice = c (MFMA c-index), offset = lm.
// A-frag from X (f32 row-major for layer 1, fp16 SLICED for layer 2).

#define GEMM_LDS_BYTES (128 * 136 * 2 + 512)

template <bool XHALF>
__device__ __forceinline__ void gemm_body(
        const void* __restrict__ Xv, const float* __restrict__ Ws,
        const float* __restrict__ Wd, const float* __restrict__ attd,
        const float* __restrict__ att,
        __half* __restrict__ Y, float* __restrict__ a_s, float* __restrict__ a_d,
        int N, int blk, char* smem) {
    _Float16 (*sWh)[136] = (_Float16(*)[136])smem;
    float* svd = (float*)(smem + 128 * 136 * 2);
    int t = threadIdx.x;

    // vd[k] = dot(Wd row k, attd)
    if (t < 128) {
        const float4* wr = (const float4*)&Wd[t * 128];
        const float4* ar = (const float4*)attd;
        float s = 0.f;
#pragma unroll 8
        for (int j = 0; j < 32; j++) {
            float4 w = wr[j], a = ar[j];
            s += w.x * a.x + w.y * a.y + w.z * a.z + w.w * a.w;
        }
        svd[t] = s;
    }
    // sWh[n][k] = (fp16) Ws[k*128+n]
#pragma unroll
    for (int i = 0; i < 16; i++) {
        int gid = t + i * 256;       // 0..4095
        int n = gid & 127, kq = gid >> 7;
        _Float16 p[4];
        p[0] = (_Float16)Ws[(kq * 4 + 0) * 128 + n];
        p[1] = (_Float16)Ws[(kq * 4 + 1) * 128 + n];
        p[2] = (_Float16)Ws[(kq * 4 + 2) * 128 + n];
        p[3] = (_Float16)Ws[(kq * 4 + 3) * 128 + n];
        *(uint2*)&sWh[n][kq * 4] = *(uint2*)p;
    }
    __syncthreads();

    int l = t & 63, wv = t >> 6;
    int quad = l >> 4, lm = l & 15;
    int rbase = blk * 64 + wv * 16;
    int arow = rbase + lm;
    bool rok = arow < N;

    f32x4 acc[8];
#pragma unroll
    for (int c = 0; c < 8; c++) acc[c] = (f32x4){0.f, 0.f, 0.f, 0.f};
    float adp = 0.f;

#pragma unroll
    for (int kc = 0; kc < 4; kc++) {
        int k0 = kc * 32 + quad * 8;
        float xf[8];
        f16x8 af;
        if constexpr (XHALF) {
            // sliced input: channels k0..k0+7 live at slice k0>>4, offset k0&15
            const __half* xp = (const __half*)Xv +
                ((size_t)(k0 >> 4) * N + arow) * 16 + (k0 & 15);
            if (rok) {
                af = *(const f16x8*)xp;
            } else {
#pragma unroll
                for (int j = 0; j < 8; j++) af[j] = (_Float16)0.f;
            }
#pragma unroll
            for (int j = 0; j < 8; j++) xf[j] = (float)af[j];
        } else {
            const float* xrow = (const float*)Xv + (size_t)arow * 128;
            if (rok) {
                *(float4*)&xf[0] = *(const float4*)&xrow[k0];
                *(float4*)&xf[4] = *(const float4*)&xrow[k0 + 4];
            } else {
#pragma unroll
                for (int j = 0; j < 8; j++) xf[j] = 0.f;
            }
#pragma unroll
            for (int j = 0; j < 8; j++) af[j] = (_Float16)xf[j];
        }
        float4 v0 = *(const float4*)&svd[k0];       // broadcast within quad
        float4 v1 = *(const float4*)&svd[k0 + 4];
        adp += xf[0] * v0.x + xf[1] * v0.y + xf[2] * v0.z + xf[3] * v0.w
             + xf[4] * v1.x + xf[5] * v1.y + xf[6] * v1.z + xf[7] * v1.w;
#pragma unroll
        for (int c = 0; c < 8; c++) {
            f16x8 bf = *(const f16x8*)&sWh[c * 16 + lm][k0];   // col n = c*16+lm
            acc[c] = __builtin_amdgcn_mfma_f32_16x16x32_f16(af, bf, acc[c], 0, 0, 0);
        }
    }

    adp += __shfl_xor(adp, 16);
    adp += __shfl_xor(adp, 32);
    if (quad == 0 && rok) a_d[arow] = adp;

    float attc[8];
#pragma unroll
    for (int c = 0; c < 8; c++) attc[c] = att[c * 16 + lm];
#pragma unroll
    for (int r = 0; r < 4; r++) {
        int grow = rbase + quad * 4 + r;
        bool gok = grow < N;
        float p = 0.f;
#pragma unroll
        for (int c = 0; c < 8; c++) {
            if (gok) Y[((size_t)c * N + grow) * 16 + lm] = __float2half(acc[c][r]);
            p += acc[c][r] * attc[c];
        }
        p += __shfl_xor(p, 1); p += __shfl_xor(p, 2); p += __shfl_xor(p, 4); p += __shfl_xor(p, 8);
        if (lm == 0 && gok) a_s[grow] = p;
    }
}

// ---------------- FUSED: layer-1 GEMM (blocks < gb) + kA3 pair placement ----------------
__global__ __launch_bounds__(256, 4) void k_fuse1(
        const float* __restrict__ X, const float* __restrict__ W1s,
        const float* __restrict__ W1d, const float* __restrict__ a1d,
        const float* __restrict__ a1s,
        __half* __restrict__ Y, float* __restrict__ a_s, float* __restrict__ a_d, int N, int gb,
        const int* __restrict__ src, const int* __restrict__ dst, int E,
        int* __restrict__ cursor, unsigned* __restrict__ pairs) {
    __shared__ __align__(16) char smem[GEMM_LDS_BYTES];
    int t = threadIdx.x;

    if ((int)blockIdx.x >= gb) {
        int* hist  = (int*)smem;          // 512 ints
        int* start = hist + 512;          // 512 ints
        hist[t] = 0; hist[t + 256] = 0;
        __syncthreads();
        int e0 = (blockIdx.x - gb) * 1024 + t * 4;
        int d[4], s[4];
        bool full = (e0 + 3 < E);
        if (full) {
            int4 dv = *(const int4*)&dst[e0];
            int4 sv = *(const int4*)&src[e0];
            d[0] = dv.x; d[1] = dv.y; d[2] = dv.z; d[3] = dv.w;
            s[0] = sv.x; s[1] = sv.y; s[2] = sv.z; s[3] = sv.w;
#pragma unroll
            for (int i = 0; i < 4; i++) atomicAdd(&hist[d[i] >> NBSHIFT], 1);
        } else {
#pragma unroll
            for (int i = 0; i < 4; i++) {
                if (e0 + i < E) { d[i] = dst[e0 + i]; s[i] = src[e0 + i]; atomicAdd(&hist[d[i] >> NBSHIFT], 1); }
                else d[i] = -1;
            }
        }
        __syncthreads();
        if (hist[t] > 0)       start[t]       = atomicAdd(&cursor[t],       hist[t]);
        if (hist[t + 256] > 0) start[t + 256] = atomicAdd(&cursor[t + 256], hist[t + 256]);
        __syncthreads();
        hist[t] = 0; hist[t + 256] = 0;   // reuse as rank counters
        __syncthreads();
#pragma unroll
        for (int i = 0; i < 4; i++) {
            if (full || (e0 + i < E)) {
                int b = d[i] >> NBSHIFT;
                int r = atomicAdd(&hist[b], 1);
                pairs[b * CAP + start[b] + r] = ((unsigned)(d[i] & (BSZ - 1)) << 17) | (unsigned)s[i];
            }
        }
        return;
    }

    gemm_body<false>(X, W1s, W1d, a1d, a1s, Y, a_s, a_d, N, blockIdx.x, smem);
}

// ---------------- standalone layer-2 GEMM (fp16 sliced input h) ----------------
__global__ __launch_bounds__(256, 4) void k_gemm2(
        const __half* __restrict__ X, const float* __restrict__ W2s,
        const float* __restrict__ W2d, const float* __restrict__ a2d,
        const float* __restrict__ a2s,
        __half* __restrict__ Y, float* __restrict__ a_s, float* __restrict__ a_d, int N) {
    __shared__ __align__(16) char smem[GEMM_LDS_BYTES];
    gemm_body<true>(X, W2s, W2d, a2d, a2s, Y, a_s, a_d, N, blockIdx.x, smem);
}

// ---------------- kB: per-bucket CSR finalize (counts/scan/place in LDS) ----------------
__global__ __launch_bounds__(256) void kB_csr(const unsigned* __restrict__ pairs,
                                              const int* __restrict__ cursor,
                                              int* __restrict__ row_start, int* __restrict__ row_end,
                                              int* __restrict__ csr_src, int N) {
    __shared__ int cnt[BSZ];
    __shared__ int cur[BSZ];
    __shared__ int sS[256];
    int b = blockIdx.x, t = threadIdx.x;
    int base = b * CAP;
    int ecnt = cursor[b];
    int nodeBase = b << NBSHIFT;
    cnt[t] = 0;
    __syncthreads();
    for (int j = t; j < ecnt; j += 256)
        atomicAdd(&cnt[pairs[base + j] >> 17], 1);
    __syncthreads();
    int c0 = cnt[t];
    sS[t] = c0; __syncthreads();
    for (int off = 1; off < 256; off <<= 1) {
        int x = (t >= off) ? sS[t - off] : 0;
        __syncthreads();
        sS[t] += x;
        __syncthreads();
    }
    int excl = sS[t] - c0;
    cur[t] = excl;
    int g = nodeBase + t;
    if (g < N) { row_start[g] = base + excl; row_end[g] = base + excl + c0; }
    __syncthreads();
    for (int j = t; j < ecnt; j += 256) {
        unsigned p = pairs[base + j];
        int r = atomicAdd(&cur[p >> 17], 1);
        csr_src[base + r] = (int)(p & 0x1FFFFu);
    }
}

// ---------------- kW: per-node normalized edge weights ----------------
// Wave per node: gather a_s[src], w = exp(leaky(a_s+a_d)), row-sum, write
// ew[slot] = {src, w/(sum+eps)}. Slice passes then just stream ew.
__global__ __launch_bounds__(256) void kW(const int* __restrict__ csr_src,
                                          const int* __restrict__ rs_, const int* __restrict__ re_,
                                          const float* __restrict__ a_s, const float* __restrict__ a_d,
                                          int2* __restrict__ ew, int N) {
    int t = threadIdx.x; int wv = t >> 6, l = t & 63;
    int n = blockIdx.x * 4 + wv;
    if (n >= N) return;
    int rs = rs_[n];
    int deg = re_[n] - rs;
    float adn = a_d[n];

    if (deg <= 64) {
        int sidx = 0; float w = 0.f;
        if (l < deg) {
            sidx = csr_src[rs + l];
            float tv = a_s[sidx] + adn;
            tv = tv > 0.f ? tv : 0.2f * tv;
            w = __expf(tv);
        }
        float dn = w;
        dn += __shfl_xor(dn, 1);  dn += __shfl_xor(dn, 2);
        dn += __shfl_xor(dn, 4);  dn += __shfl_xor(dn, 8);
        dn += __shfl_xor(dn, 16); dn += __shfl_xor(dn, 32);
        float inv = 1.f / (dn + 1e-16f);
        if (l < deg) ew[rs + l] = make_int2(sidx, __float_as_int(w * inv));
    } else {
        float dn = 0.f;
        for (int b = 0; b < deg; b += 64) {
            if (b + l < deg) {
                int s = csr_src[rs + b + l];
                float tv = a_s[s] + adn;
                tv = tv > 0.f ? tv : 0.2f * tv;
                dn += __expf(tv);
            }
        }
        dn += __shfl_xor(dn, 1);  dn += __shfl_xor(dn, 2);
        dn += __shfl_xor(dn, 4);  dn += __shfl_xor(dn, 8);
        dn += __shfl_xor(dn, 16); dn += __shfl_xor(dn, 32);
        float inv = 1.f / (dn + 1e-16f);
        for (int b = 0; b < deg; b += 64) {
            if (b + l < deg) {
                int s = csr_src[rs + b + l];
                float tv = a_s[s] + adn;
                tv = tv > 0.f ? tv : 0.2f * tv;
                ew[rs + b + l] = make_int2(s, __float_as_int(__expf(tv) * inv));
            }
        }
    }
}

// ---------------- k_slice: XCD-stationary sliced aggregation ----------------
// slice = blockIdx % 8 -> lands on XCD (blockIdx%8) via dispatch round-robin, so
// each XCD's 3.2MB slice of xs stays L2-resident. Quad per node: 4 edges x 4
// sub-lanes (8B each) per iteration; ew streamed nontemporal (don't evict xs).

__device__ __forceinline__ void fma_mix2(float& a0, float& a1, unsigned h2, float w) {
    asm("v_fma_mix_f32 %0, %1, %2, %0 op_sel_hi:[1,0,0]" : "+v"(a0) : "v"(h2), "v"(w));
    asm("v_fma_mix_f32 %0, %1, %2, %0 op_sel:[1,0,0] op_sel_hi:[1,0,0]" : "+v"(a1) : "v"(h2), "v"(w));
}

template <bool HEAD>
__global__ __launch_bounds__(256) void k_slice(const int2* __restrict__ ew,
                                               const int* __restrict__ rs_, const int* __restrict__ re_,
                                               const __half* __restrict__ xs,   // sliced [8][N][16]
                                               const float* __restrict__ bias,
                                               const float* __restrict__ Wl, const float* __restrict__ bl,
                                               void* __restrict__ outv, int N) {
    int t = threadIdx.x; int wv = t >> 6, l = t & 63;
    int slice = blockIdx.x & (NSLICE - 1);
    int g = blockIdx.x >> 3;
    if (g * 16 + wv * 4 >= N) return;         // wave-uniform tail guard
    int q   = l >> 4;        // node slot within wave (0..3)
    int ql  = l & 15;
    int qe  = ql >> 2;       // edge slot (0..3)
    int sub = ql & 3;        // channel group (0..3) -> channels sub*4..+3 of slice
    int n = g * 16 + wv * 4 + q;
    bool nok = n < N;
    int rs = 0, deg = 0;
    if (nok) { rs = rs_[n]; deg = re_[n] - rs; }
    const __half* xb = xs + (size_t)slice * N * 16;

    float a0 = 0.f, a1 = 0.f, a2 = 0.f, a3 = 0.f;
    for (int b = 0; b < deg; b += 4) {
        int i = b + qe;
        long long pv = 0;
        if (i < deg) pv = __builtin_nontemporal_load((const long long*)(ew + rs + i));
        int   sidx = (int)(unsigned)(pv & 0xffffffffll);
        float w    = __int_as_float((int)(pv >> 32));
        uint2 u = *(const uint2*)&xb[(size_t)sidx * 16 + sub * 4];
        fma_mix2(a0, a1, u.x, w);
        fma_mix2(a2, a3, u.y, w);
    }
    // reduce across edge slots (lane bits 2,3)
    a0 += __shfl_xor(a0, 4); a0 += __shfl_xor(a0, 8);
    a1 += __shfl_xor(a1, 4); a1 += __shfl_xor(a1, 8);
    a2 += __shfl_xor(a2, 4); a2 += __shfl_xor(a2, 8);
    a3 += __shfl_xor(a3, 4); a3 += __shfl_xor(a3, 8);

    int ch = slice * 16 + sub * 4;
    float4 bv = *(const float4*)&bias[ch];
    float h0 = a0 + bv.x; h0 = h0 > 0.f ? h0 : 0.f;
    float h1 = a1 + bv.y; h1 = h1 > 0.f ? h1 : 0.f;
    float h2 = a2 + bv.z; h2 = h2 > 0.f ? h2 : 0.f;
    float h3 = a3 + bv.w; h3 = h3 > 0.f ? h3 : 0.f;

    if (HEAD) {
        float4 wA = *(const float4*)&Wl[2 * ch];      // {c0o0,c0o1,c1o0,c1o1}
        float4 wB = *(const float4*)&Wl[2 * ch + 4];  // {c2o0,c2o1,c3o0,c3o1}
        float p0 = h0 * wA.x + h1 * wA.z + h2 * wB.x + h3 * wB.z;
        float p1 = h0 * wA.y + h1 * wA.w + h2 * wB.y + h3 * wB.w;
        p0 += __shfl_xor(p0, 1); p0 += __shfl_xor(p0, 2);
        p1 += __shfl_xor(p1, 1); p1 += __shfl_xor(p1, 2);
        if (ql == 0 && nok) {
            if (slice == 0) { p0 += bl[0]; p1 += bl[1]; }
            float* out = (float*)outv;
            atomicAdd(&out[2 * n],     p0);
            atomicAdd(&out[2 * n + 1], p1);
        }
    } else {
        if (qe == 0 && nok) {
            __half hh[4];
            hh[0] = __float2half(h0); hh[1] = __float2half(h1);
            hh[2] = __float2half(h2); hh[3] = __float2half(h3);
            __half* hout = (__half*)outv;
            *(uint2*)&hout[((size_t)slice * N + n) * 16 + sub * 4] = *(uint2*)hh;
        }
    }
}

// ---------------- launch ----------------

extern "C" void kernel_launch(void* const* d_in, const int* in_sizes, int n_in,
                              void* d_out, int out_size, void* d_ws, size_t ws_size,
                              hipStream_t stream) {
    const float* x   = (const float*)d_in[0];
    const int*   ei  = (const int*)d_in[1];
    const float* W1s = (const float*)d_in[2];
    const float* W1d = (const float*)d_in[3];
    const float* a1s = (const float*)d_in[4];
    const float* a1d = (const float*)d_in[5];
    const float* b1  = (const float*)d_in[6];
    const float* W2s = (const float*)d_in[7];
    const float* W2d = (const float*)d_in[8];
    const float* a2s = (const float*)d_in[9];
    const float* a2d = (const float*)d_in[10];
    const float* b2  = (const float*)d_in[11];
    const float* Wl  = (const float*)d_in[12];
    const float* bl  = (const float*)d_in[13];
    float* out = (float*)d_out;

    int N = in_sizes[0] / 128;
    int E = in_sizes[1] / 2;
    const int* srcA = ei;
    const int* dstA = ei + E;
    int NB = (N + BSZ - 1) >> NBSHIFT;

    // workspace layout
    __half* xs = (__half*)d_ws;                     // [8][N][16] fp16 (25.6 MB)
    __half* h  = xs + (size_t)N * 128;              // [8][N][16] fp16 (pairs aliases this)
    float* as_ = (float*)(h + (size_t)N * 128);     // N
    float* ad_ = as_ + N;                           // N
    int* row_start = (int*)(ad_ + N);               // N
    int* row_end   = row_start + N;                 // N
    int* csr_src   = row_end + N;                   // NB*CAP (8 MB)
    int* cursor    = csr_src + (size_t)NB * CAP;    // NB (zeroed via memset)
    int2* ew = (int2*)(((uintptr_t)(cursor + NB) + 15) & ~(uintptr_t)15);  // NB*CAP int2 (16 MB)
    unsigned* pairs = (unsigned*)h;                 // NB*CAP dwords; written disp k_fuse1,
                                                    // read kB_csr; h first written k_slice<false>

    int gb = (N + 63) / 64;
    int EB = (E + 1023) / 1024;
    int wb = (N + 3) / 4;
    int sgrid = NSLICE * ((N + 15) / 16);

    // 1) zero bucket cursors + head output (accumulated via atomics)
    hipMemsetAsync(cursor, 0, (size_t)NB * 4, stream);
    hipMemsetAsync(out, 0, (size_t)N * 2 * sizeof(float), stream);

    // 2) layer-1 GEMM (sliced Y) fused with kA3 pair placement
    k_fuse1<<<gb + EB, 256, 0, stream>>>(x, W1s, W1d, a1d, a1s, xs, as_, ad_, N, gb,
                                         srcA, dstA, E, cursor, pairs);

    // 3) per-bucket CSR finalize
    kB_csr<<<NB, 256, 0, stream>>>(pairs, cursor, row_start, row_end, csr_src, N);

    // 4) layer-1 normalized edge weights
    kW<<<wb, 256, 0, stream>>>(csr_src, row_start, row_end, as_, ad_, ew, N);

    // 5) layer-1 sliced aggregation (writes fp16 sliced h)
    k_slice<false><<<sgrid, 256, 0, stream>>>(ew, row_start, row_end, xs, b1, nullptr, nullptr, h, N);

    // 6) layer-2 GEMM (sliced fp16 input, sliced Y into xs)
    k_gemm2<<<gb, 256, 0, stream>>>(h, W2s, W2d, a2d, a2s, xs, as_, ad_, N);

    // 7) layer-2 normalized edge weights
    kW<<<wb, 256, 0, stream>>>(csr_src, row_start, row_end, as_, ad_, ew, N);

    // 8) layer-2 sliced aggregation + head (atomic partial sums)
    k_slice<true><<<sgrid, 256, 0, stream>>>(ew, row_start, row_end, xs, b2, Wl, bl, out, N);
}

// Round 4
// 319.704 us; speedup vs baseline: 1.9058x; 1.9058x over previous
//
#include <hip/hip_runtime.h>
#include <hip/hip_fp16.h>

#define NBSHIFT 8
#define BSZ     256     // nodes per bucket
#define CAP     5120    // fixed bucket capacity (mean 4092, sigma 64 -> +16 sigma)

typedef _Float16 f16x8 __attribute__((ext_vector_type(8)));
typedef float    f32x4 __attribute__((ext_vector_type(4)));

// ---------------- self-contained MFMA GEMM body ----------------
// Per block: (a) vd = W_d @ att_d into LDS (128 threads, L1-resident row dots);
// (b) W_s transposed+cvt to fp16 LDS sWh[n][k] (coalesced loads, 8B LDS stores);
// then Y(fp16)=X@W via mfma_f32_16x16x32_f16, wave owns 16 rows.
// A-frag from X (f32 row-major for layer 1, fp16 row-major for layer 2).
// C/D: col=lane&15, row=quad*4+reg.

#define GEMM_LDS_BYTES (128 * 136 * 2 + 512)

template <bool XHALF>
__device__ __forceinline__ void gemm_body(
        const void* __restrict__ Xv, const float* __restrict__ Ws,
        const float* __restrict__ Wd, const float* __restrict__ attd,
        const float* __restrict__ att,
        __half* __restrict__ Y, float* __restrict__ a_s, float* __restrict__ a_d,
        int N, int blk, char* smem) {
    _Float16 (*sWh)[136] = (_Float16(*)[136])smem;
    float* svd = (float*)(smem + 128 * 136 * 2);
    int t = threadIdx.x;

    // vd[k] = dot(Wd row k, attd)
    if (t < 128) {
        const float4* wr = (const float4*)&Wd[t * 128];
        const float4* ar = (const float4*)attd;
        float s = 0.f;
#pragma unroll 8
        for (int j = 0; j < 32; j++) {
            float4 w = wr[j], a = ar[j];
            s += w.x * a.x + w.y * a.y + w.z * a.z + w.w * a.w;
        }
        svd[t] = s;
    }
    // sWh[n][k] = (fp16) Ws[k*128+n]
#pragma unroll
    for (int i = 0; i < 16; i++) {
        int gid = t + i * 256;       // 0..4095
        int n = gid & 127, kq = gid >> 7;
        _Float16 p[4];
        p[0] = (_Float16)Ws[(kq * 4 + 0) * 128 + n];
        p[1] = (_Float16)Ws[(kq * 4 + 1) * 128 + n];
        p[2] = (_Float16)Ws[(kq * 4 + 2) * 128 + n];
        p[3] = (_Float16)Ws[(kq * 4 + 3) * 128 + n];
        *(uint2*)&sWh[n][kq * 4] = *(uint2*)p;
    }
    __syncthreads();

    int l = t & 63, wv = t >> 6;
    int quad = l >> 4, lm = l & 15;
    int rbase = blk * 64 + wv * 16;
    int arow = rbase + lm;
    bool rok = arow < N;

    f32x4 acc[8];
#pragma unroll
    for (int c = 0; c < 8; c++) acc[c] = (f32x4){0.f, 0.f, 0.f, 0.f};
    float adp = 0.f;

#pragma unroll
    for (int kc = 0; kc < 4; kc++) {
        int k0 = kc * 32 + quad * 8;
        float xf[8];
        f16x8 af;
        if constexpr (XHALF) {
            const __half* xrow = (const __half*)Xv + (size_t)arow * 128;
            if (rok) {
                af = *(const f16x8*)&xrow[k0];
            } else {
#pragma unroll
                for (int j = 0; j < 8; j++) af[j] = (_Float16)0.f;
            }
#pragma unroll
            for (int j = 0; j < 8; j++) xf[j] = (float)af[j];
        } else {
            const float* xrow = (const float*)Xv + (size_t)arow * 128;
            if (rok) {
                *(float4*)&xf[0] = *(const float4*)&xrow[k0];
                *(float4*)&xf[4] = *(const float4*)&xrow[k0 + 4];
            } else {
#pragma unroll
                for (int j = 0; j < 8; j++) xf[j] = 0.f;
            }
#pragma unroll
            for (int j = 0; j < 8; j++) af[j] = (_Float16)xf[j];
        }
        float4 v0 = *(const float4*)&svd[k0];       // broadcast within quad
        float4 v1 = *(const float4*)&svd[k0 + 4];
        adp += xf[0] * v0.x + xf[1] * v0.y + xf[2] * v0.z + xf[3] * v0.w
             + xf[4] * v1.x + xf[5] * v1.y + xf[6] * v1.z + xf[7] * v1.w;
#pragma unroll
        for (int c = 0; c < 8; c++) {
            f16x8 bf = *(const f16x8*)&sWh[c * 16 + lm][k0];   // col n = c*16+lm
            acc[c] = __builtin_amdgcn_mfma_f32_16x16x32_f16(af, bf, acc[c], 0, 0, 0);
        }
    }

    adp += __shfl_xor(adp, 16);
    adp += __shfl_xor(adp, 32);
    if (quad == 0 && rok) a_d[arow] = adp;

    float attc[8];
#pragma unroll
    for (int c = 0; c < 8; c++) attc[c] = att[c * 16 + lm];
#pragma unroll
    for (int r = 0; r < 4; r++) {
        int grow = rbase + quad * 4 + r;
        bool gok = grow < N;
        float p = 0.f;
#pragma unroll
        for (int c = 0; c < 8; c++) {
            if (gok) Y[(size_t)grow * 128 + c * 16 + lm] = __float2half(acc[c][r]);
            p += acc[c][r] * attc[c];
        }
        p += __shfl_xor(p, 1); p += __shfl_xor(p, 2); p += __shfl_xor(p, 4); p += __shfl_xor(p, 8);
        if (lm == 0 && gok) a_s[grow] = p;
    }
}

// ---------------- FUSED: layer-1 GEMM (blocks < gb) + kA3 pair placement ----------------
__global__ __launch_bounds__(256, 4) void k_fuse1(
        const float* __restrict__ X, const float* __restrict__ W1s,
        const float* __restrict__ W1d, const float* __restrict__ a1d,
        const float* __restrict__ a1s,
        __half* __restrict__ Y, float* __restrict__ a_s, float* __restrict__ a_d, int N, int gb,
        const int* __restrict__ src, const int* __restrict__ dst, int E,
        int* __restrict__ cursor, unsigned* __restrict__ pairs) {
    __shared__ __align__(16) char smem[GEMM_LDS_BYTES];
    int t = threadIdx.x;

    if ((int)blockIdx.x >= gb) {
        int* hist  = (int*)smem;          // 512 ints
        int* start = hist + 512;          // 512 ints
        hist[t] = 0; hist[t + 256] = 0;
        __syncthreads();
        int e0 = (blockIdx.x - gb) * 1024 + t * 4;
        int d[4], s[4];
        bool full = (e0 + 3 < E);
        if (full) {
            int4 dv = *(const int4*)&dst[e0];
            int4 sv = *(const int4*)&src[e0];
            d[0] = dv.x; d[1] = dv.y; d[2] = dv.z; d[3] = dv.w;
            s[0] = sv.x; s[1] = sv.y; s[2] = sv.z; s[3] = sv.w;
#pragma unroll
            for (int i = 0; i < 4; i++) atomicAdd(&hist[d[i] >> NBSHIFT], 1);
        } else {
#pragma unroll
            for (int i = 0; i < 4; i++) {
                if (e0 + i < E) { d[i] = dst[e0 + i]; s[i] = src[e0 + i]; atomicAdd(&hist[d[i] >> NBSHIFT], 1); }
                else d[i] = -1;
            }
        }
        __syncthreads();
        if (hist[t] > 0)       start[t]       = atomicAdd(&cursor[t],       hist[t]);
        if (hist[t + 256] > 0) start[t + 256] = atomicAdd(&cursor[t + 256], hist[t + 256]);
        __syncthreads();
        hist[t] = 0; hist[t + 256] = 0;   // reuse as rank counters
        __syncthreads();
#pragma unroll
        for (int i = 0; i < 4; i++) {
            if (full || (e0 + i < E)) {
                int b = d[i] >> NBSHIFT;
                int r = atomicAdd(&hist[b], 1);
                pairs[b * CAP + start[b] + r] = ((unsigned)(d[i] & (BSZ - 1)) << 17) | (unsigned)s[i];
            }
        }
        return;
    }

    gemm_body<false>(X, W1s, W1d, a1d, a1s, Y, a_s, a_d, N, blockIdx.x, smem);
}

// ---------------- standalone layer-2 GEMM (fp16 input h) ----------------
__global__ __launch_bounds__(256, 4) void k_gemm2(
        const __half* __restrict__ X, const float* __restrict__ W2s,
        const float* __restrict__ W2d, const float* __restrict__ a2d,
        const float* __restrict__ a2s,
        __half* __restrict__ Y, float* __restrict__ a_s, float* __restrict__ a_d, int N) {
    __shared__ __align__(16) char smem[GEMM_LDS_BYTES];
    gemm_body<true>(X, W2s, W2d, a2d, a2s, Y, a_s, a_d, N, blockIdx.x, smem);
}

// ---------------- kB: per-bucket CSR finalize (counts/scan/place in LDS) ----------------
__global__ __launch_bounds__(256) void kB_csr(const unsigned* __restrict__ pairs,
                                              const int* __restrict__ cursor,
                                              int* __restrict__ row_start, int* __restrict__ row_end,
                                              int* __restrict__ csr_src, int N) {
    __shared__ int cnt[BSZ];
    __shared__ int cur[BSZ];
    __shared__ int sS[256];
    int b = blockIdx.x, t = threadIdx.x;
    int base = b * CAP;
    int ecnt = cursor[b];
    int nodeBase = b << NBSHIFT;
    cnt[t] = 0;
    __syncthreads();
    for (int j = t; j < ecnt; j += 256)
        atomicAdd(&cnt[pairs[base + j] >> 17], 1);
    __syncthreads();
    int c0 = cnt[t];
    sS[t] = c0; __syncthreads();
    for (int off = 1; off < 256; off <<= 1) {
        int x = (t >= off) ? sS[t - off] : 0;
        __syncthreads();
        sS[t] += x;
        __syncthreads();
    }
    int excl = sS[t] - c0;
    cur[t] = excl;
    int g = nodeBase + t;
    if (g < N) { row_start[g] = base + excl; row_end[g] = base + excl + c0; }
    __syncthreads();
    for (int j = t; j < ecnt; j += 256) {
        unsigned p = pairs[base + j];
        int r = atomicAdd(&cur[p >> 17], 1);
        csr_src[base + r] = (int)(p & 0x1FFFFu);
    }
}

// ---------------- per-dst-node softmax + aggregation: quad-per-node ----------------
// Wave = 4 nodes (one per quad), block = 16 nodes. Per round of 16 edges/node:
// phase 1: lane (ns=l>>4, es=l&15) computes w = exp(leaky(a_s[src]+a_d)) for edge
//   es of node ns -> all 64 lanes productive at mean degree 16; (idx,w) to
//   wave-private LDS. Denominator accumulates per-lane, one 4-shfl reduce at end.
// phase 2: quad q sweeps its node's valid slots with 4-deep gather chains; each
//   lane owns channels es*8..es*8+7 exclusively -> no cross-lane feature reduce.
//   Each load instruction carries 4 different edges (one per quad): >=4 edges in
//   flight per wave even if the compiler serializes chains; up to 16 if not.
// fma_mix: acc_f32 += w_f32 * x_f16 in one VALU op (exact cvt+fma rounding).

__device__ __forceinline__ void fma_mix2(float& a0, float& a1, unsigned h2, float w) {
    asm("v_fma_mix_f32 %0, %1, %2, %0 op_sel_hi:[1,0,0]" : "+v"(a0) : "v"(h2), "v"(w));
    asm("v_fma_mix_f32 %0, %1, %2, %0 op_sel:[1,0,0] op_sel_hi:[1,0,0]" : "+v"(a1) : "v"(h2), "v"(w));
}

#define ACC_MIX(u, wj)  do {                                    \
    const unsigned* _w32 = (const unsigned*)&(u);               \
    fma_mix2(acc[0], acc[1], _w32[0], (wj));                    \
    fma_mix2(acc[2], acc[3], _w32[1], (wj));                    \
    fma_mix2(acc[4], acc[5], _w32[2], (wj));                    \
    fma_mix2(acc[6], acc[7], _w32[3], (wj));                    \
} while (0)

template <bool HEAD>
__global__ __launch_bounds__(256, 6) void k_agg(const int* __restrict__ csr_src, const int* __restrict__ rs_,
                                                const int* __restrict__ re_,
                                                const float* __restrict__ a_s, const float* __restrict__ a_d,
                                                const __half* __restrict__ xs, const float* __restrict__ bias,
                                                const float* __restrict__ Wl, const float* __restrict__ bl,
                                                void* __restrict__ outv, int N) {
    __shared__ int2 sP[4][4][16];
    int t = threadIdx.x; int wv = t >> 6, l = t & 63;
    int q = l >> 4, es = l & 15;
    int n = blockIdx.x * 16 + wv * 4 + q;
    bool nok = n < N;
    int rs0 = 0, deg = 0;
    if (nok) { rs0 = rs_[n]; deg = re_[n] - rs0; }
    float adn = nok ? a_d[n] : 0.f;
    const int* cs = csr_src + rs0;
    int c = es * 8;

    int R = (deg + 15) >> 4;            // rounds for this node
    R = max(R, __shfl_xor(R, 16));      // wave-uniform max
    R = max(R, __shfl_xor(R, 32));

    float acc[8];
#pragma unroll
    for (int k = 0; k < 8; k++) acc[k] = 0.f;
    float dnl = 0.f;
    int2 (*sq)[16] = sP[wv];            // wave-private

    for (int r = 0; r < R; ++r) {
        // ---- phase 1: parallel weight compute for 4 nodes x 16 edges ----
        int i = r * 16 + es;
        int idx = 0; float w = 0.f;
        if (i < deg) {
            idx = cs[i];
            float tv = a_s[idx] + adn;
            tv = tv > 0.f ? tv : 0.2f * tv;
            w = __expf(tv);
        }
        dnl += w;
        sq[q][es] = make_int2(idx, __float_as_int(w));  // same-wave LDS: lockstep ordering

        // ---- phase 2: quad q gathers its node's rows, 4-deep chains ----
        int rem = deg - r * 16;
        int mcq = rem >= 16 ? 16 : (rem > 0 ? ((rem + 3) & ~3) : 0);
        const int2* spq = sq[q];
        for (int e = 0; e < mcq; e += 4) {
            int4 pA = *(const int4*)&spq[e];        // edges e, e+1
            int4 pB = *(const int4*)&spq[e + 2];    // edges e+2, e+3
            uint4 u0 = *(const uint4*)&xs[(size_t)pA.x * 128 + c];
            uint4 u1 = *(const uint4*)&xs[(size_t)pA.z * 128 + c];
            uint4 u2 = *(const uint4*)&xs[(size_t)pB.x * 128 + c];
            uint4 u3 = *(const uint4*)&xs[(size_t)pB.z * 128 + c];
            ACC_MIX(u0, __int_as_float(pA.y));
            ACC_MIX(u1, __int_as_float(pA.w));
            ACC_MIX(u2, __int_as_float(pB.y));
            ACC_MIX(u3, __int_as_float(pB.w));
        }
    }

    // denominator: sum w over the 16 edge-slot lanes of this quad
    dnl += __shfl_xor(dnl, 1);
    dnl += __shfl_xor(dnl, 2);
    dnl += __shfl_xor(dnl, 4);
    dnl += __shfl_xor(dnl, 8);
    float inv = 1.f / (dnl + 1e-16f);

    float hv[8];
    float4 b0 = *(const float4*)&bias[c];
    float4 b1 = *(const float4*)&bias[c + 4];
    float bb[8] = {b0.x, b0.y, b0.z, b0.w, b1.x, b1.y, b1.z, b1.w};
#pragma unroll
    for (int k = 0; k < 8; k++) {
        float v = acc[k] * inv + bb[k];
        hv[k] = v > 0.f ? v : 0.f;
    }

    if (HEAD) {
        float p0 = 0.f, p1 = 0.f;
#pragma unroll
        for (int k = 0; k < 8; k++) {
            p0 += hv[k] * Wl[2 * (c + k)];
            p1 += hv[k] * Wl[2 * (c + k) + 1];
        }
        p0 += __shfl_xor(p0, 1); p0 += __shfl_xor(p0, 2);
        p0 += __shfl_xor(p0, 4); p0 += __shfl_xor(p0, 8);
        p1 += __shfl_xor(p1, 1); p1 += __shfl_xor(p1, 2);
        p1 += __shfl_xor(p1, 4); p1 += __shfl_xor(p1, 8);
        if (es == 0 && nok) {
            float* out = (float*)outv;
            out[2 * n]     = p0 + bl[0];
            out[2 * n + 1] = p1 + bl[1];
        }
    } else {
        // lane exclusively owns 8 channels: direct 16B fp16 store, 256B/quad
        if (nok) {
            __half* hout = (__half*)outv;
            __half hb[8];
#pragma unroll
            for (int k = 0; k < 8; k++) hb[k] = __float2half(hv[k]);
            *(uint4*)&hout[(size_t)n * 128 + c] = *(uint4*)hb;
        }
    }
}

// ---------------- launch ----------------

extern "C" void kernel_launch(void* const* d_in, const int* in_sizes, int n_in,
                              void* d_out, int out_size, void* d_ws, size_t ws_size,
                              hipStream_t stream) {
    const float* x   = (const float*)d_in[0];
    const int*   ei  = (const int*)d_in[1];
    const float* W1s = (const float*)d_in[2];
    const float* W1d = (const float*)d_in[3];
    const float* a1s = (const float*)d_in[4];
    const float* a1d = (const float*)d_in[5];
    const float* b1  = (const float*)d_in[6];
    const float* W2s = (const float*)d_in[7];
    const float* W2d = (const float*)d_in[8];
    const float* a2s = (const float*)d_in[9];
    const float* a2d = (const float*)d_in[10];
    const float* b2  = (const float*)d_in[11];
    const float* Wl  = (const float*)d_in[12];
    const float* bl  = (const float*)d_in[13];
    float* out = (float*)d_out;

    int N = in_sizes[0] / 128;
    int E = in_sizes[1] / 2;
    const int* srcA = ei;
    const int* dstA = ei + E;
    int NB = (N + BSZ - 1) >> NBSHIFT;

    // workspace layout
    __half* xs = (__half*)d_ws;                     // N*128 fp16  (25.6 MB)
    __half* h  = xs + (size_t)N * 128;              // N*128 fp16  (pairs aliases this)
    float* as_ = (float*)(h + (size_t)N * 128);     // N
    float* ad_ = as_ + N;                           // N
    int* row_start = (int*)(ad_ + N);               // N
    int* row_end   = row_start + N;                 // N
    int* csr_src   = row_end + N;                   // NB*CAP (8 MB)
    int* cursor    = csr_src + (size_t)NB * CAP;    // NB (zeroed via memset)
    unsigned* pairs = (unsigned*)h;                 // NB*CAP dwords (8 MB) <= h (25.6 MB);
                                                    // pairs written k_fuse1, read kB_csr;
                                                    // h first written k_agg<false> — no overlap

    int gb = (N + 63) / 64;
    int EB = (E + 1023) / 1024;
    int ab = (N + 15) / 16;

    // 1) zero bucket cursors (1.5 KB DMA)
    hipMemsetAsync(cursor, 0, (size_t)NB * 4, stream);

    // 2) layer-1 GEMM (self-contained: W-transpose + vd in LDS) fused with kA3
    k_fuse1<<<gb + EB, 256, 0, stream>>>(x, W1s, W1d, a1d, a1s, xs, as_, ad_, N, gb,
                                         srcA, dstA, E, cursor, pairs);

    // 3) per-bucket CSR finalize
    kB_csr<<<NB, 256, 0, stream>>>(pairs, cursor, row_start, row_end, csr_src, N);

    // 4) layer-1 aggregation (writes fp16 h)
    k_agg<false><<<ab, 256, 0, stream>>>(csr_src, row_start, row_end, as_, ad_, xs, b1, nullptr, nullptr, h, N);

    // 5) layer-2 GEMM (self-contained, fp16 input)
    k_gemm2<<<gb, 256, 0, stream>>>(h, W2s, W2d, a2d, a2s, xs, as_, ad_, N);

    // 6) layer-2 aggregation + head
    k_agg<true><<<ab, 256, 0, stream>>>(csr_src, row_start, row_end, as_, ad_, xs, b2, Wl, bl, out, N);
}